// Round 2
// baseline (306.213 us; speedup 1.0000x reference)
//
#include <hip/hip_runtime.h>
#include <hip/hip_bf16.h>
#include <math.h>

typedef __bf16 bf16_t;
typedef bf16_t bf16x8 __attribute__((ext_vector_type(8)));
typedef float f32x4 __attribute__((ext_vector_type(4)));

#define BB 4
#define SS 2048
#define HH 16
#define DMODEL 1024
#define DHEAD 64

// Q is pre-scaled by 1/sqrt(64) * log2(e) so attention probs are exp2(q.k)
#define QSCALE 0.18033688011112042f

__device__ inline unsigned short f2bf(float f) {
    union { __hip_bfloat16 h; unsigned short u; } cvt;
    cvt.h = __float2bfloat16(f);
    return cvt.u;
}

// async global->LDS, 16B per lane. LDS dest = wave-uniform base + lane*16.
__device__ __forceinline__ void gll16(const unsigned short* g, unsigned short* l) {
    __builtin_amdgcn_global_load_lds(
        (const __attribute__((address_space(1))) unsigned int*)(g),
        (__attribute__((address_space(3))) unsigned int*)(l), 16, 0, 0);
}

// ---------------- pack kernels ----------------

__global__ void pack_x(const float* __restrict__ x, unsigned short* __restrict__ xb) {
    int i = blockIdx.x * 256 + threadIdx.x;
    const float4 v = ((const float4*)x)[i];
    unsigned short o[4] = { f2bf(v.x), f2bf(v.y), f2bf(v.z), f2bf(v.w) };
    *(uint2*)(xb + 4 * (size_t)i) = *(uint2*)o;
}

// WqkvT[n][k], n = mat*1024 + h*64 + d, k = m.  W_* is [H][DM][DH].
__global__ void pack_wqkv(const float* __restrict__ wq, const float* __restrict__ wk,
                          const float* __restrict__ wv, unsigned short* __restrict__ out) {
    int idx = blockIdx.x * 256 + threadIdx.x;
    int k  = idx & 1023;
    int n  = idx >> 10;
    int mat = n >> 10;
    int n1 = n & 1023;
    int h = n1 >> 6, d = n1 & 63;
    const float* w = (mat == 0) ? wq : (mat == 1) ? wk : wv;
    out[idx] = f2bf(w[(h << 16) + (k << 6) + d]);
}

// WoT[n][k], n = m_model, k = h*64+dh.  W_O is [H][DH][DM] = row-major [k][n].
__global__ void pack_wo(const float* __restrict__ wo, unsigned short* __restrict__ out) {
    int idx = blockIdx.x * 256 + threadIdx.x;
    int k = idx & 1023, n = idx >> 10;
    out[idx] = f2bf(wo[(k << 10) + n]);
}

// ---------------- GEMM 1: 256x256 tile, 8-phase schedule (T2+T3+T4+T5) ----------------
// qkv = x @ WqkvT^T + bias.  Q (pre-scaled by QSCALE), K -> [B,H,S,64]; V -> [B,H,64,S].
//
// 512 threads = 8 waves (2M x 4N), per-wave 128x64 output, BK=64, LDS 128 KiB
// (2 buffers x (A 256x64 + B 256x64) bf16). Per K-tile: 4 phases of 16 MFMA.
// Phase order per wave: (mh0,njA) (mh0,njB) (mh1,njB) (mh1,njA) -> ds_reads 12/4/8/0.
// LDS layout swizzle: 16B granule g of row r stored at g^(r&7) (pre-swizzled global
// source, linear global_load_lds dest; reads use granule (kk*4+quad)^(l15&7) -> 2-way
// conflicts only = free).
// Staging stream (1 half-tile = 2 gll16/thread per phase):
//   p0: (t+1).B1  p1: (t+1).A1  (into buf^1; its tile t-1 fully consumed)
//   p2: (t+2).B0  p3: (t+2).A0  (into current buf; B dead after p1, A dead after p2)
// Boundary (end of p3): vmcnt(4) = drain all but newest 2 half-tiles -> tile t+1 fully
// landed before its first read; vmcnt(0) at the last boundary (stages beyond end skipped).

template <bool SWAP>
__device__ __forceinline__ void mf16(f32x4& d, bf16x8 a, bf16x8 b) {
    if constexpr (SWAP)
        d = __builtin_amdgcn_mfma_f32_16x16x32_bf16(b, a, d, 0, 0, 0);  // D rows = n
    else
        d = __builtin_amdgcn_mfma_f32_16x16x32_bf16(a, b, d, 0, 0, 0);  // D rows = m
}

#define GBAR()   __builtin_amdgcn_s_barrier()
#define SCHEDB() __builtin_amdgcn_sched_barrier(0)
#define WLGKM0() asm volatile("s_waitcnt lgkmcnt(0)" ::: "memory")

template <bool SWAP>
__device__ __forceinline__ void kloop256(
    unsigned short (*sAb)[256][64], unsigned short (*sBb)[256][64],
    const unsigned short* gA0, const unsigned short* gA1,
    const unsigned short* gB0, const unsigned short* gB1,
    int w, int wr, int wc, int l15, int quad, int lo,
    f32x4 (&acc)[8][4])
{
    auto STAGE = [&](const unsigned short* g, unsigned short* lb, int T) {
        const unsigned short* s = g + T * 64;
        gll16(s, lb + w * 8 * 64);
        gll16(s + 64 * 1024, lb + (64 + w * 8) * 64);
    };

    // prologue: stream order (0).B0,(0).A0,(0).B1,(0).A1,(1).B0,(1).A0
    STAGE(gB0, &sBb[0][0][0],   0);
    STAGE(gA0, &sAb[0][0][0],   0);
    STAGE(gB1, &sBb[0][128][0], 0);
    STAGE(gA1, &sAb[0][128][0], 0);
    STAGE(gB0, &sBb[1][0][0],   1);
    STAGE(gA0, &sAb[1][0][0],   1);
    asm volatile("s_waitcnt vmcnt(4)" ::: "memory");   // tile0 fully landed
    GBAR();

#pragma unroll 2
    for (int kt = 0; kt < 16; ++kt) {
        const int bsel = kt & 1;
        unsigned short (*A)[64] = sAb[bsel];
        unsigned short (*B)[64] = sBb[bsel];
        bf16x8 a0[4][2], a1[4][2], bA[2][2], bB[2][2];

        // ---- p0: (mh0, njA); reads a0 (8) + bA (4); stage (t+1).B1
#pragma unroll
        for (int mi = 0; mi < 4; mi++) {
            a0[mi][0] = *(const bf16x8*)&A[wr * 128 + mi * 16 + l15][(quad ^ lo) * 8];
            a0[mi][1] = *(const bf16x8*)&A[wr * 128 + mi * 16 + l15][((4 | quad) ^ lo) * 8];
        }
#pragma unroll
        for (int nj = 0; nj < 2; nj++) {
            bA[nj][0] = *(const bf16x8*)&B[wc * 64 + nj * 16 + l15][(quad ^ lo) * 8];
            bA[nj][1] = *(const bf16x8*)&B[wc * 64 + nj * 16 + l15][((4 | quad) ^ lo) * 8];
        }
        if (kt + 1 < 16) STAGE(gB1, &sBb[(kt + 1) & 1][128][0], kt + 1);
        GBAR();
        WLGKM0();
        SCHEDB();
        __builtin_amdgcn_s_setprio(1);
#pragma unroll
        for (int mi = 0; mi < 4; mi++)
#pragma unroll
            for (int nj = 0; nj < 2; nj++) {
                mf16<SWAP>(acc[mi][nj], a0[mi][0], bA[nj][0]);
                mf16<SWAP>(acc[mi][nj], a0[mi][1], bA[nj][1]);
            }
        __builtin_amdgcn_s_setprio(0);
        SCHEDB();
        GBAR();

        // ---- p1: (mh0, njB); reads bB (4); stage (t+1).A1
#pragma unroll
        for (int nj = 0; nj < 2; nj++) {
            bB[nj][0] = *(const bf16x8*)&B[wc * 64 + (nj + 2) * 16 + l15][(quad ^ lo) * 8];
            bB[nj][1] = *(const bf16x8*)&B[wc * 64 + (nj + 2) * 16 + l15][((4 | quad) ^ lo) * 8];
        }
        if (kt + 1 < 16) STAGE(gA1, &sAb[(kt + 1) & 1][128][0], kt + 1);
        GBAR();
        WLGKM0();
        SCHEDB();
        __builtin_amdgcn_s_setprio(1);
#pragma unroll
        for (int mi = 0; mi < 4; mi++)
#pragma unroll
            for (int nj = 0; nj < 2; nj++) {
                mf16<SWAP>(acc[mi][nj + 2], a0[mi][0], bB[nj][0]);
                mf16<SWAP>(acc[mi][nj + 2], a0[mi][1], bB[nj][1]);
            }
        __builtin_amdgcn_s_setprio(0);
        SCHEDB();
        GBAR();

        // ---- p2: (mh1, njB); reads a1 (8); stage (t+2).B0
#pragma unroll
        for (int mi = 0; mi < 4; mi++) {
            a1[mi][0] = *(const bf16x8*)&A[wr * 128 + 64 + mi * 16 + l15][(quad ^ lo) * 8];
            a1[mi][1] = *(const bf16x8*)&A[wr * 128 + 64 + mi * 16 + l15][((4 | quad) ^ lo) * 8];
        }
        if (kt + 2 < 16) STAGE(gB0, &sBb[kt & 1][0][0], kt + 2);
        GBAR();
        WLGKM0();
        SCHEDB();
        __builtin_amdgcn_s_setprio(1);
#pragma unroll
        for (int mi = 0; mi < 4; mi++)
#pragma unroll
            for (int nj = 0; nj < 2; nj++) {
                mf16<SWAP>(acc[4 + mi][nj + 2], a1[mi][0], bB[nj][0]);
                mf16<SWAP>(acc[4 + mi][nj + 2], a1[mi][1], bB[nj][1]);
            }
        __builtin_amdgcn_s_setprio(0);
        SCHEDB();
        GBAR();

        // ---- p3: (mh1, njA); no reads; stage (t+2).A0; boundary wait
        if (kt + 2 < 16) STAGE(gA0, &sAb[kt & 1][0][0], kt + 2);
        GBAR();
        WLGKM0();
        SCHEDB();
        __builtin_amdgcn_s_setprio(1);
#pragma unroll
        for (int mi = 0; mi < 4; mi++)
#pragma unroll
            for (int nj = 0; nj < 2; nj++) {
                mf16<SWAP>(acc[4 + mi][nj], a1[mi][0], bA[nj][0]);
                mf16<SWAP>(acc[4 + mi][nj], a1[mi][1], bA[nj][1]);
            }
        __builtin_amdgcn_s_setprio(0);
        SCHEDB();
        if (kt == 14) {
            asm volatile("s_waitcnt vmcnt(0)" ::: "memory");   // last tile: drain all
        } else if (kt < 14) {
            asm volatile("s_waitcnt vmcnt(4)" ::: "memory");   // keep 2 half-tiles in flight
        }
        GBAR();
    }
}

__global__ __launch_bounds__(512, 2) void gemm_qkv8(
    const unsigned short* __restrict__ xb,    // [8192][1024]
    const unsigned short* __restrict__ wT,    // [3072][1024]
    const float* __restrict__ bq, const float* __restrict__ bk, const float* __restrict__ bv,
    unsigned short* __restrict__ qws, unsigned short* __restrict__ kws,
    unsigned short* __restrict__ vtw)         // [64][64][2048]
{
    __shared__ __align__(16) unsigned short sA[2][256][64];   // 64 KiB
    __shared__ __align__(16) unsigned short sB[2][256][64];   // 64 KiB

    const int t = threadIdx.x;
    const int lane = t & 63;
    const int w = t >> 6;            // 0..7
    const int quad = lane >> 4;
    const int l15 = lane & 15;
    const int lo = l15 & 7;
    const int wr = w >> 2;           // 0..1
    const int wc = w & 3;            // 0..3
    const int n0 = blockIdx.x * 256;
    const int m0 = blockIdx.y * 256;
    const int mat = n0 >> 10;        // uniform per block (256 | 1024)

    // staging source: lane covers row w*8+(lane>>3), source granule (lane&7)^(lane>>3)
    const int sr8 = lane >> 3;
    const size_t soff = (size_t)(w * 8 + sr8) * 1024 + (size_t)(((lane & 7) ^ sr8) * 8);
    const unsigned short* gA0 = xb + (size_t)m0 * 1024 + soff;
    const unsigned short* gA1 = xb + (size_t)(m0 + 128) * 1024 + soff;
    const unsigned short* gB0 = wT + (size_t)n0 * 1024 + soff;
    const unsigned short* gB1 = wT + (size_t)(n0 + 128) * 1024 + soff;

    f32x4 acc[8][4] = {};

    const int b = m0 >> 11;
    const int m0r = m0 & 2047;

    if (mat != 2) {
        kloop256<true>(sA, sB, gA0, gA1, gB0, gB1, w, wr, wc, l15, quad, lo, acc);
        // swapped D: lane holds 4 consecutive n (=d) at fixed s -> uint2 stores
        const float* bias_p = (mat == 0) ? bq : bk;
        const float scale = (mat == 0) ? QSCALE : 1.0f;
        unsigned short* dst = (mat == 0) ? qws : kws;
#pragma unroll
        for (int nj = 0; nj < 4; nj++) {
            const int noff = wc * 64 + nj * 16 + quad * 4;     // 0..255
            const int nmat = (n0 & 1023) + noff;
            const int h = nmat >> 6;
            const int dbase = nmat & 63;
            const float4 bv4 = *(const float4*)(bias_p + h * 64 + dbase);
            const float bias_r[4] = { bv4.x, bv4.y, bv4.z, bv4.w };
#pragma unroll
            for (int mig = 0; mig < 8; mig++) {
                const int s = m0r + wr * 128 + mig * 16 + l15;
                unsigned short pk[4];
#pragma unroll
                for (int r = 0; r < 4; r++) pk[r] = f2bf((acc[mig][nj][r] + bias_r[r]) * scale);
                *(uint2*)(dst + (size_t)((b * 16 + h) * 2048 + s) * 64 + dbase) = *(uint2*)pk;
            }
        }
    } else {
        kloop256<false>(sA, sB, gA0, gA1, gB0, gB1, w, wr, wc, l15, quad, lo, acc);
        // normal D: lane holds 4 consecutive s at fixed n -> uint2 into V^T
#pragma unroll
        for (int nj = 0; nj < 4; nj++) {
            const int n1 = (n0 & 1023) + wc * 64 + nj * 16 + l15;
            const int h = n1 >> 6, d = n1 & 63;
            const float bias = bv[h * 64 + d];
#pragma unroll
            for (int mig = 0; mig < 8; mig++) {
                const int s0 = m0r + wr * 128 + mig * 16 + quad * 4;
                unsigned short pk[4];
#pragma unroll
                for (int r = 0; r < 4; r++) pk[r] = f2bf(acc[mig][nj][r] + bias);
                *(uint2*)(vtw + ((size_t)(b * 16 + h) * 64 + d) * 2048 + s0) = *(uint2*)pk;
            }
        }
    }
}

// ---------------- attention v5 (unchanged from r1) ----------------

__global__ __launch_bounds__(256) void attn3(
    const unsigned short* __restrict__ qws,
    const unsigned short* __restrict__ kws,
    const unsigned short* __restrict__ vtw,   // [bh][64][2048]
    unsigned short* __restrict__ zb)          // [8192][1024], col = h*64+d
{
    __shared__ __align__(16) unsigned short Ks[64 * 64];
    __shared__ __align__(16) unsigned short Vs[64 * 64];    // [d][key]
    __shared__ __align__(16) unsigned short Ps[4 * 16 * 64];

    const int t = threadIdx.x;
    const int lane = t & 63;
    const int w = t >> 6;
    const int quad = lane >> 4;
    const int l15 = lane & 15;
    const int hi = l15 >> 3;
    const int lo = l15 & 7;

    const int qt = 31 - (blockIdx.x >> 6);   // longest blocks dispatched first
    const int bh = blockIdx.x & 63;
    const int q0 = qt * 64;
    const int qbase = q0 + w * 16;
    const size_t base = (size_t)bh * SS * DHEAD;
    const unsigned short* Q = qws + base;
    const unsigned short* K = kws + base;
    const unsigned short* Vt = vtw + base;   // [64][2048]

    bf16x8 qf0 = *(const bf16x8*)(Q + (size_t)(qbase + l15) * 64 + quad * 8);
    bf16x8 qf1 = *(const bf16x8*)(Q + (size_t)(qbase + l15) * 64 + 32 + quad * 8);

    f32x4 o[4] = {};          // swapped PV: o[dt] rows = d (dt*16+quad*4+r), col = q (l15)
    float lsum[4] = {0.f, 0.f, 0.f, 0.f};
    unsigned short* Pw = Ps + w * 16 * 64;

    // staging: thread t covers row sr, original col-granules (t&3) and (t&3)+4
    const int sr = t >> 2;
    const int g0 = t & 3;
    const int sw0 = ((g0 ^ (sr & 7)) << 3);
    const int sw1 = (((g0 + 4) ^ (sr & 7)) << 3);
    unsigned short* ksw = Ks + sr * 64;
    unsigned short* vsw = Vs + sr * 64;
    const unsigned short* Kg = K + (size_t)sr * 64 + g0 * 8;
    const unsigned short* Vg = Vt + (size_t)sr * 2048 + g0 * 8;

    // fragment reads: want original granules quad / quad+4 of row with row&7==l15&7
    const int gq0 = ((quad ^ lo) << 3);
    const int gq1 = (((quad + 4) ^ lo) << 3);

    const int nch = qt + 1;

    // prologue: prefetch chunk 0 into registers
    uint4 kr0 = *(const uint4*)(Kg);
    uint4 kr1 = *(const uint4*)(Kg + 32);
    uint4 vr0 = *(const uint4*)(Vg);
    uint4 vr1 = *(const uint4*)(Vg + 32);

    for (int c = 0; c < nch; c++) {
        __builtin_amdgcn_sched_barrier(0);
        __builtin_amdgcn_s_barrier();          // LDS free: all waves consumed chunk c-1
        *(uint4*)(ksw + sw0) = kr0;
        *(uint4*)(ksw + sw1) = kr1;
        *(uint4*)(vsw + sw0) = vr0;
        *(uint4*)(vsw + sw1) = vr1;
        if (c + 1 < nch) {                     // issue next chunk's loads; NOT waited here
            const unsigned short* kp = Kg + (size_t)(c + 1) * 64 * 64;
            const unsigned short* vp = Vg + (size_t)(c + 1) * 64;
            kr0 = *(const uint4*)(kp);
            kr1 = *(const uint4*)(kp + 32);
            vr0 = *(const uint4*)(vp);
            vr1 = *(const uint4*)(vp + 32);
        }
        asm volatile("s_waitcnt lgkmcnt(0)" ::: "memory");   // my ds_writes done (vmcnt stays)
        __builtin_amdgcn_s_barrier();          // LDS ready
        __builtin_amdgcn_sched_barrier(0);

        // scores for 16 q-rows x 64 keys: 8 MFMA (D: row=q quad*4+r, col=key l15)
        f32x4 s[4];
        __builtin_amdgcn_s_setprio(1);
#pragma unroll
        for (int sub = 0; sub < 4; sub++) {
            const unsigned short* kr = Ks + (sub * 16 + l15) * 64;
            bf16x8 kf0 = *(const bf16x8*)(kr + gq0);
            bf16x8 kf1 = *(const bf16x8*)(kr + gq1);
            f32x4 sv = {};
            sv = __builtin_amdgcn_mfma_f32_16x16x32_bf16(qf0, kf0, sv, 0, 0, 0);
            sv = __builtin_amdgcn_mfma_f32_16x16x32_bf16(qf1, kf1, sv, 0, 0, 0);
            s[sub] = sv;
        }
        __builtin_amdgcn_s_setprio(0);

        // fixed-max softmax: p = exp2(s) since Q carries 0.125*log2e
        const int kb = c * 64;
        if (c == nch - 1) {
            const int qg = qbase + quad * 4;
#pragma unroll
            for (int sub = 0; sub < 4; sub++) {
                const int key = kb + sub * 16 + l15;
#pragma unroll
                for (int r = 0; r < 4; r++) {
                    float p = (key > qg + r) ? 0.f : exp2f(s[sub][r]);
                    lsum[r] += p;
                    const int q = quad * 4 + r;
                    Pw[q * 64 + (((sub * 2 + hi) ^ (q & 7)) << 3) + lo] = f2bf(p);
                }
            }
        } else {
#pragma unroll
            for (int sub = 0; sub < 4; sub++)
#pragma unroll
                for (int r = 0; r < 4; r++) {
                    float p = exp2f(s[sub][r]);
                    lsum[r] += p;
                    const int q = quad * 4 + r;
                    Pw[q * 64 + (((sub * 2 + hi) ^ (q & 7)) << 3) + lo] = f2bf(p);
                }
        }
        // wave-private D-layout -> fragment-layout round trip
        asm volatile("s_waitcnt lgkmcnt(0)" ::: "memory");
        bf16x8 pf0 = *(const bf16x8*)(Pw + l15 * 64 + gq0);
        bf16x8 pf1 = *(const bf16x8*)(Pw + l15 * 64 + gq1);
        __builtin_amdgcn_s_setprio(1);
#pragma unroll
        for (int dt = 0; dt < 4; dt++) {
            const unsigned short* vrp = Vs + (dt * 16 + l15) * 64;
            bf16x8 vf0 = *(const bf16x8*)(vrp + gq0);
            bf16x8 vf1 = *(const bf16x8*)(vrp + gq1);
            // swapped: A=V (m=d), B=P (n=q)
            o[dt] = __builtin_amdgcn_mfma_f32_16x16x32_bf16(vf0, pf0, o[dt], 0, 0, 0);
            o[dt] = __builtin_amdgcn_mfma_f32_16x16x32_bf16(vf1, pf1, o[dt], 0, 0, 0);
        }
        __builtin_amdgcn_s_setprio(0);
    }

    // full row sums (valid per lane for q = quad*4+r after 16-lane reduce)
#pragma unroll
    for (int r = 0; r < 4; r++) {
        float v = lsum[r];
        v += __shfl_xor(v, 1);
        v += __shfl_xor(v, 2);
        v += __shfl_xor(v, 4);
        v += __shfl_xor(v, 8);
        lsum[r] = v;
    }
    // redistribute: this lane needs 1/sum for q = l15
    const int srcl = (l15 >> 2) << 4;
    float t0 = __shfl(lsum[0], srcl);
    float t1 = __shfl(lsum[1], srcl);
    float t2 = __shfl(lsum[2], srcl);
    float t3 = __shfl(lsum[3], srcl);
    const int rr = l15 & 3;
    float den = (rr == 0) ? t0 : (rr == 1) ? t1 : (rr == 2) ? t2 : t3;
    const float inv = 1.0f / den;

    const int b = bh >> 4, h = bh & 15;
    const int q = qbase + l15;
    unsigned short* zrow = zb + (size_t)(b * 2048 + q) * 1024 + h * 64 + quad * 4;
#pragma unroll
    for (int dt = 0; dt < 4; dt++) {
        unsigned short pk[4];
#pragma unroll
        for (int r = 0; r < 4; r++) pk[r] = f2bf(o[dt][r] * inv);
        *(uint2*)(zrow + dt * 16) = *(uint2*)pk;
    }
}

// ---------------- GEMM 2 (m97 structure, swapped operands): out = z @ WoT^T + bO ----------------

__global__ __launch_bounds__(256) void gemm_out(
    const unsigned short* __restrict__ zb,    // [8192][1024]
    const unsigned short* __restrict__ wT,    // [1024][1024]
    const float* __restrict__ bo,
    float* __restrict__ out)
{
    __shared__ __align__(16) unsigned short lA[128 * 32];
    __shared__ __align__(16) unsigned short lB[128 * 32];
    const int t = threadIdx.x;
    const int lane = t & 63;
    const int w = t >> 6;
    const int quad = lane >> 4;
    const int l15 = lane & 15;
    const int n0 = blockIdx.x * 128;
    const int m0 = blockIdx.y * 128;
    const int wm = (w >> 1) * 64;
    const int wn = (w & 1) * 64;

    f32x4 acc[4][4] = {};

    const int srow = w * 16 + (lane >> 2);
    const int scol = (lane & 3) * 8;
    const unsigned short* Ag0 = zb + (size_t)(m0 + srow) * 1024 + scol;
    const unsigned short* Ag1 = Ag0 + (size_t)64 * 1024;
    const unsigned short* Bg0 = wT + (size_t)(n0 + srow) * 1024 + scol;
    const unsigned short* Bg1 = Bg0 + (size_t)64 * 1024;
    unsigned short* lA0 = lA + (w * 16) * 32;
    unsigned short* lA1 = lA + (64 + w * 16) * 32;
    unsigned short* lB0 = lB + (w * 16) * 32;
    unsigned short* lB1 = lB + (64 + w * 16) * 32;

    for (int kt = 0; kt < 1024; kt += 32) {
        __syncthreads();
        gll16(Ag0 + kt, lA0);
        gll16(Ag1 + kt, lA1);
        gll16(Bg0 + kt, lB0);
        gll16(Bg1 + kt, lB1);
        __syncthreads();
        bf16x8 af[4], bfr[4];
#pragma unroll
        for (int i = 0; i < 4; i++) {
            af[i]  = *(const bf16x8*)(lA + (wm + i * 16 + l15) * 32 + quad * 8);
            bfr[i] = *(const bf16x8*)(lB + (wn + i * 16 + l15) * 32 + quad * 8);
        }
#pragma unroll
        for (int i = 0; i < 4; i++)
#pragma unroll
            for (int j = 0; j < 4; j++)
                acc[i][j] = __builtin_amdgcn_mfma_f32_16x16x32_bf16(bfr[j], af[i], acc[i][j], 0, 0, 0);
    }

    // swapped D: lane holds 4 consecutive n at fixed s -> float4 stores
#pragma unroll
    for (int j = 0; j < 4; j++) {
        const int nbase = n0 + wn + j * 16 + quad * 4;
        const float4 bv4 = *(const float4*)(bo + nbase);
#pragma unroll
        for (int i = 0; i < 4; i++) {
            const int s = m0 + wm + i * 16 + l15;
            float4 v;
            v.x = acc[i][j][0] + bv4.x;
            v.y = acc[i][j][1] + bv4.y;
            v.z = acc[i][j][2] + bv4.z;
            v.w = acc[i][j][3] + bv4.w;
            *(float4*)(out + (size_t)s * 1024 + nbase) = v;
        }
    }
}

// ---------------- launch ----------------

extern "C" void kernel_launch(void* const* d_in, const int* in_sizes, int n_in,
                              void* d_out, int out_size, void* d_ws, size_t ws_size,
                              hipStream_t stream) {
    const float* x  = (const float*)d_in[0];
    const float* WQ = (const float*)d_in[1];
    const float* WK = (const float*)d_in[2];
    const float* WV = (const float*)d_in[3];
    const float* WO = (const float*)d_in[4];
    const float* bQ = (const float*)d_in[5];
    const float* bK = (const float*)d_in[6];
    const float* bV = (const float*)d_in[7];
    const float* bO = (const float*)d_in[8];
    float* out = (float*)d_out;

    char* ws = (char*)d_ws;
    unsigned short* xb   = (unsigned short*)ws;                   // 16 MB (reused as zbuf)
    unsigned short* wqkv = (unsigned short*)(ws + (16u << 20));   // 6 MB
    unsigned short* woT  = (unsigned short*)(ws + (22u << 20));   // 2 MB
    unsigned short* qws  = (unsigned short*)(ws + (24u << 20));   // 16 MB
    unsigned short* kws  = (unsigned short*)(ws + (40u << 20));   // 16 MB
    unsigned short* vtw  = (unsigned short*)(ws + (56u << 20));   // 16 MB, [bh][64][2048]
    unsigned short* zbuf = xb;                                    // x dead after gemm_qkv

    pack_x<<<8192, 256, 0, stream>>>(x, xb);
    pack_wqkv<<<(3072 * 1024) / 256, 256, 0, stream>>>(WQ, WK, WV, wqkv);
    pack_wo<<<(1024 * 1024) / 256, 256, 0, stream>>>(WO, woT);
    gemm_qkv8<<<dim3(12, 32), 512, 0, stream>>>(xb, wqkv, bQ, bK, bV, qws, kws, vtw);
    attn3<<<2048, 256, 0, stream>>>(qws, kws, vtw, zbuf);
    gemm_out<<<dim3(8, 64), 256, 0, stream>>>(zbuf, woT, bO, out);
}

// Round 5
// 305.769 us; speedup vs baseline: 1.0015x; 1.0015x over previous
//
#include <hip/hip_runtime.h>
#include <hip/hip_bf16.h>
#include <math.h>

typedef __bf16 bf16_t;
typedef bf16_t bf16x8 __attribute__((ext_vector_type(8)));
typedef float f32x4 __attribute__((ext_vector_type(4)));

#define BB 4
#define SS 2048
#define HH 16
#define DMODEL 1024
#define DHEAD 64

// Q is pre-scaled by 1/sqrt(64) * log2(e) so attention probs are exp2(q.k)
#define QSCALE 0.18033688011112042f

__device__ inline unsigned short f2bf(float f) {
    union { __hip_bfloat16 h; unsigned short u; } cvt;
    cvt.h = __float2bfloat16(f);
    return cvt.u;
}

// async global->LDS, 16B per lane. LDS dest = wave-uniform base + lane*16.
__device__ __forceinline__ void gll16(const unsigned short* g, unsigned short* l) {
    __builtin_amdgcn_global_load_lds(
        (const __attribute__((address_space(1))) unsigned int*)(g),
        (__attribute__((address_space(3))) unsigned int*)(l), 16, 0, 0);
}

// ---------------- pack kernels ----------------

__global__ void pack_x(const float* __restrict__ x, unsigned short* __restrict__ xb) {
    int i = blockIdx.x * 256 + threadIdx.x;
    const float4 v = ((const float4*)x)[i];
    unsigned short o[4] = { f2bf(v.x), f2bf(v.y), f2bf(v.z), f2bf(v.w) };
    *(uint2*)(xb + 4 * (size_t)i) = *(uint2*)o;
}

// WqkvT[n][k], n = mat*1024 + h*64 + d, k = m.  W_* is [H][DM][DH].
__global__ void pack_wqkv(const float* __restrict__ wq, const float* __restrict__ wk,
                          const float* __restrict__ wv, unsigned short* __restrict__ out) {
    int idx = blockIdx.x * 256 + threadIdx.x;
    int k  = idx & 1023;
    int n  = idx >> 10;
    int mat = n >> 10;
    int n1 = n & 1023;
    int h = n1 >> 6, d = n1 & 63;
    const float* w = (mat == 0) ? wq : (mat == 1) ? wk : wv;
    out[idx] = f2bf(w[(h << 16) + (k << 6) + d]);
}

// WoT[n][k], n = m_model, k = h*64+dh.  W_O is [H][DH][DM] = row-major [k][n].
__global__ void pack_wo(const float* __restrict__ wo, unsigned short* __restrict__ out) {
    int idx = blockIdx.x * 256 + threadIdx.x;
    int k = idx & 1023, n = idx >> 10;
    out[idx] = f2bf(wo[(k << 10) + n]);
}

// ---------------- 256x256 8-phase K-loop (T2+T3+T4+T5) ----------------
// 512 threads = 8 waves (2M x 4N), per-wave 128x64 output, BK=64.
// Ping/pong in FOUR DISTINCT __shared__ objects so SIInsertWaitcnts' LDS-DMA
// alias check can disprove aliasing between current-buffer ds_reads and
// in-flight global_load_lds DMAs to the other buffer (round-2's single
// sA[2][...] object forced conservative vmcnt drains every phase = the m218
// drain-0 degenerate case). Compiler-visible C++ ds_reads (the round-3 asm
// read experiment was miscompiled -> NaN; reverted).
// Granule swizzle g^=row&7 via pre-swizzled global source + swizzled reads.
// Staging per kt: p0 (t+1).B1hi, p1 (t+1).A1hi, p2 (t+2).B0lo, p3 (t+2).A0lo.
// Boundary vmcnt(4): keep the 2 newest half-tiles in flight; vmcnt(0) at kt=14.

template <bool SWAP>
__device__ __forceinline__ void mf16(f32x4& d, bf16x8 a, bf16x8 b) {
    if constexpr (SWAP)
        d = __builtin_amdgcn_mfma_f32_16x16x32_bf16(b, a, d, 0, 0, 0);  // D rows = n
    else
        d = __builtin_amdgcn_mfma_f32_16x16x32_bf16(a, b, d, 0, 0, 0);  // D rows = m
}

#define GBAR()   __builtin_amdgcn_s_barrier()
#define SCHEDB() __builtin_amdgcn_sched_barrier(0)
#define WLGKM0() asm volatile("s_waitcnt lgkmcnt(0)" ::: "memory")

__device__ __forceinline__ void stage2(const unsigned short* g, unsigned short* lb,
                                       int T, int w) {
    const unsigned short* s = g + T * 64;
    gll16(s, lb + w * 8 * 64);
    gll16(s + 64 * 1024, lb + (64 + w * 8) * 64);
}

template <bool SWAP>
__device__ __forceinline__ void ktstep(
    unsigned short (*Ac)[64], unsigned short (*Bc)[64],   // current tile buffers
    unsigned short (*An)[64], unsigned short (*Bn)[64],   // next tile buffers
    const unsigned short* gA0, const unsigned short* gA1,
    const unsigned short* gB0, const unsigned short* gB1,
    int kt, int w, int wr, int wc, int l15, int quad, int lo,
    f32x4 (&acc)[8][4])
{
    bf16x8 a0f[4][2], a1f[4][2], bAf[2][2], bBf[2][2];
    const int c0 = (quad ^ lo) * 8;
    const int c1 = ((4 | quad) ^ lo) * 8;

    // ---- p0: reads a0 (8) + bA (4); stage (t+1).B1hi
#pragma unroll
    for (int mi = 0; mi < 4; mi++) {
        a0f[mi][0] = *(const bf16x8*)&Ac[wr * 128 + mi * 16 + l15][c0];
        a0f[mi][1] = *(const bf16x8*)&Ac[wr * 128 + mi * 16 + l15][c1];
    }
#pragma unroll
    for (int nj = 0; nj < 2; nj++) {
        bAf[nj][0] = *(const bf16x8*)&Bc[wc * 64 + nj * 16 + l15][c0];
        bAf[nj][1] = *(const bf16x8*)&Bc[wc * 64 + nj * 16 + l15][c1];
    }
    if (kt + 1 < 16) stage2(gB1, &Bn[128][0], kt + 1, w);
    GBAR();
    WLGKM0();
    SCHEDB();
    __builtin_amdgcn_s_setprio(1);
#pragma unroll
    for (int mi = 0; mi < 4; mi++)
#pragma unroll
        for (int nj = 0; nj < 2; nj++) {
            mf16<SWAP>(acc[mi][nj], a0f[mi][0], bAf[nj][0]);
            mf16<SWAP>(acc[mi][nj], a0f[mi][1], bAf[nj][1]);
        }
    __builtin_amdgcn_s_setprio(0);
    SCHEDB();
    GBAR();

    // ---- p1: reads bB (4); stage (t+1).A1hi
#pragma unroll
    for (int nj = 0; nj < 2; nj++) {
        bBf[nj][0] = *(const bf16x8*)&Bc[wc * 64 + (nj + 2) * 16 + l15][c0];
        bBf[nj][1] = *(const bf16x8*)&Bc[wc * 64 + (nj + 2) * 16 + l15][c1];
    }
    if (kt + 1 < 16) stage2(gA1, &An[128][0], kt + 1, w);
    GBAR();
    WLGKM0();
    SCHEDB();
    __builtin_amdgcn_s_setprio(1);
#pragma unroll
    for (int mi = 0; mi < 4; mi++)
#pragma unroll
        for (int nj = 0; nj < 2; nj++) {
            mf16<SWAP>(acc[mi][nj + 2], a0f[mi][0], bBf[nj][0]);
            mf16<SWAP>(acc[mi][nj + 2], a0f[mi][1], bBf[nj][1]);
        }
    __builtin_amdgcn_s_setprio(0);
    SCHEDB();
    GBAR();

    // ---- p2: reads a1 (8); stage (t+2).B0lo (into Bc: its lower half is dead)
#pragma unroll
    for (int mi = 0; mi < 4; mi++) {
        a1f[mi][0] = *(const bf16x8*)&Ac[wr * 128 + 64 + mi * 16 + l15][c0];
        a1f[mi][1] = *(const bf16x8*)&Ac[wr * 128 + 64 + mi * 16 + l15][c1];
    }
    if (kt + 2 < 16) stage2(gB0, &Bc[0][0], kt + 2, w);
    GBAR();
    WLGKM0();
    SCHEDB();
    __builtin_amdgcn_s_setprio(1);
#pragma unroll
    for (int mi = 0; mi < 4; mi++)
#pragma unroll
        for (int nj = 0; nj < 2; nj++) {
            mf16<SWAP>(acc[4 + mi][nj + 2], a1f[mi][0], bBf[nj][0]);
            mf16<SWAP>(acc[4 + mi][nj + 2], a1f[mi][1], bBf[nj][1]);
        }
    __builtin_amdgcn_s_setprio(0);
    SCHEDB();
    GBAR();

    // ---- p3: no reads; stage (t+2).A0lo; boundary wait
    if (kt + 2 < 16) stage2(gA0, &Ac[0][0], kt + 2, w);
    GBAR();
    WLGKM0();
    SCHEDB();
    __builtin_amdgcn_s_setprio(1);
#pragma unroll
    for (int mi = 0; mi < 4; mi++)
#pragma unroll
        for (int nj = 0; nj < 2; nj++) {
            mf16<SWAP>(acc[4 + mi][nj], a1f[mi][0], bAf[nj][0]);
            mf16<SWAP>(acc[4 + mi][nj], a1f[mi][1], bAf[nj][1]);
        }
    __builtin_amdgcn_s_setprio(0);
    SCHEDB();
    if (kt == 14) {
        asm volatile("s_waitcnt vmcnt(0)" ::: "memory");   // last staged tile: drain all
    } else if (kt < 14) {
        asm volatile("s_waitcnt vmcnt(4)" ::: "memory");   // keep 2 half-tiles in flight
    }
    GBAR();
}

template <bool SWAP>
__device__ __forceinline__ void kloop256(
    unsigned short (*A0)[64], unsigned short (*A1)[64],
    unsigned short (*B0)[64], unsigned short (*B1)[64],
    const unsigned short* gA0, const unsigned short* gA1,
    const unsigned short* gB0, const unsigned short* gB1,
    int w, int wr, int wc, int l15, int quad, int lo,
    f32x4 (&acc)[8][4])
{
    // prologue: stream order (0).B0,(0).A0,(0).B1,(0).A1,(1).B0,(1).A0
    stage2(gB0, &B0[0][0],   0, w);
    stage2(gA0, &A0[0][0],   0, w);
    stage2(gB1, &B0[128][0], 0, w);
    stage2(gA1, &A0[128][0], 0, w);
    stage2(gB0, &B1[0][0],   1, w);
    stage2(gA0, &A1[0][0],   1, w);
    asm volatile("s_waitcnt vmcnt(4)" ::: "memory");   // tile0 fully landed
    GBAR();

    for (int i = 0; i < 8; ++i) {
        ktstep<SWAP>(A0, B0, A1, B1, gA0, gA1, gB0, gB1, 2 * i,     w, wr, wc, l15, quad, lo, acc);
        ktstep<SWAP>(A1, B1, A0, B0, gA0, gA1, gB0, gB1, 2 * i + 1, w, wr, wc, l15, quad, lo, acc);
    }
}

// ---------------- GEMM 1: qkv = x @ WqkvT^T + bias ----------------

__global__ __launch_bounds__(512, 2) void gemm_qkv8(
    const unsigned short* __restrict__ xb,    // [8192][1024]
    const unsigned short* __restrict__ wT,    // [3072][1024]
    const float* __restrict__ bq, const float* __restrict__ bk, const float* __restrict__ bv,
    unsigned short* __restrict__ qws, unsigned short* __restrict__ kws,
    unsigned short* __restrict__ vtw)         // [64][64][2048]
{
    __shared__ __align__(16) unsigned short A0s[256][64];   // 4 x 32 KiB, DISTINCT objects
    __shared__ __align__(16) unsigned short A1s[256][64];
    __shared__ __align__(16) unsigned short B0s[256][64];
    __shared__ __align__(16) unsigned short B1s[256][64];

    const int t = threadIdx.x;
    const int lane = t & 63;
    const int w = t >> 6;            // 0..7
    const int quad = lane >> 4;
    const int l15 = lane & 15;
    const int lo = l15 & 7;
    const int wr = w >> 2;           // 0..1
    const int wc = w & 3;            // 0..3
    const int n0 = blockIdx.x * 256;
    const int m0 = blockIdx.y * 256;
    const int mat = n0 >> 10;        // uniform per block (256 | 1024)

    // staging source: lane covers row w*8+(lane>>3), source granule (lane&7)^(lane>>3)
    const int sr8 = lane >> 3;
    const size_t soff = (size_t)(w * 8 + sr8) * 1024 + (size_t)(((lane & 7) ^ sr8) * 8);
    const unsigned short* gA0 = xb + (size_t)m0 * 1024 + soff;
    const unsigned short* gA1 = xb + (size_t)(m0 + 128) * 1024 + soff;
    const unsigned short* gB0 = wT + (size_t)n0 * 1024 + soff;
    const unsigned short* gB1 = wT + (size_t)(n0 + 128) * 1024 + soff;

    f32x4 acc[8][4] = {};

    const int b = m0 >> 11;
    const int m0r = m0 & 2047;

    if (mat != 2) {
        kloop256<true>(A0s, A1s, B0s, B1s, gA0, gA1, gB0, gB1, w, wr, wc, l15, quad, lo, acc);
        // swapped D: lane holds 4 consecutive n (=d) at fixed s -> uint2 stores
        const float* bias_p = (mat == 0) ? bq : bk;
        const float scale = (mat == 0) ? QSCALE : 1.0f;
        unsigned short* dst = (mat == 0) ? qws : kws;
#pragma unroll
        for (int nj = 0; nj < 4; nj++) {
            const int noff = wc * 64 + nj * 16 + quad * 4;     // 0..255
            const int nmat = (n0 & 1023) + noff;
            const int h = nmat >> 6;
            const int dbase = nmat & 63;
            const float4 bv4 = *(const float4*)(bias_p + h * 64 + dbase);
            const float bias_r[4] = { bv4.x, bv4.y, bv4.z, bv4.w };
#pragma unroll
            for (int mig = 0; mig < 8; mig++) {
                const int s = m0r + wr * 128 + mig * 16 + l15;
                unsigned short pk[4];
#pragma unroll
                for (int r = 0; r < 4; r++) pk[r] = f2bf((acc[mig][nj][r] + bias_r[r]) * scale);
                *(uint2*)(dst + (size_t)((b * 16 + h) * 2048 + s) * 64 + dbase) = *(uint2*)pk;
            }
        }
    } else {
        kloop256<false>(A0s, A1s, B0s, B1s, gA0, gA1, gB0, gB1, w, wr, wc, l15, quad, lo, acc);
        // normal D: lane holds 4 consecutive s at fixed n -> uint2 into V^T
#pragma unroll
        for (int nj = 0; nj < 4; nj++) {
            const int n1 = (n0 & 1023) + wc * 64 + nj * 16 + l15;
            const int h = n1 >> 6, d = n1 & 63;
            const float bias = bv[h * 64 + d];
#pragma unroll
            for (int mig = 0; mig < 8; mig++) {
                const int s0 = m0r + wr * 128 + mig * 16 + quad * 4;
                unsigned short pk[4];
#pragma unroll
                for (int r = 0; r < 4; r++) pk[r] = f2bf(acc[mig][nj][r] + bias);
                *(uint2*)(vtw + ((size_t)(b * 16 + h) * 64 + d) * 2048 + s0) = *(uint2*)pk;
            }
        }
    }
}

// ---------------- GEMM 2: out = z @ WoT^T + bO (same template) ----------------

__global__ __launch_bounds__(512, 2) void gemm_out8(
    const unsigned short* __restrict__ zb,    // [8192][1024]
    const unsigned short* __restrict__ wT,    // [1024][1024]
    const float* __restrict__ bo,
    float* __restrict__ out)
{
    __shared__ __align__(16) unsigned short A0s[256][64];
    __shared__ __align__(16) unsigned short A1s[256][64];
    __shared__ __align__(16) unsigned short B0s[256][64];
    __shared__ __align__(16) unsigned short B1s[256][64];

    const int t = threadIdx.x;
    const int lane = t & 63;
    const int w = t >> 6;
    const int quad = lane >> 4;
    const int l15 = lane & 15;
    const int lo = l15 & 7;
    const int wr = w >> 2;
    const int wc = w & 3;
    const int n0 = blockIdx.x * 256;
    const int m0 = blockIdx.y * 256;

    const int sr8 = lane >> 3;
    const size_t soff = (size_t)(w * 8 + sr8) * 1024 + (size_t)(((lane & 7) ^ sr8) * 8);
    const unsigned short* gA0 = zb + (size_t)m0 * 1024 + soff;
    const unsigned short* gA1 = zb + (size_t)(m0 + 128) * 1024 + soff;
    const unsigned short* gB0 = wT + (size_t)n0 * 1024 + soff;
    const unsigned short* gB1 = wT + (size_t)(n0 + 128) * 1024 + soff;

    f32x4 acc[8][4] = {};

    kloop256<true>(A0s, A1s, B0s, B1s, gA0, gA1, gB0, gB1, w, wr, wc, l15, quad, lo, acc);

    // swapped D: lane holds 4 consecutive n at fixed s -> float4 stores
#pragma unroll
    for (int nj = 0; nj < 4; nj++) {
        const int nbase = n0 + wc * 64 + nj * 16 + quad * 4;
        const float4 bv4 = *(const float4*)(bo + nbase);
#pragma unroll
        for (int mig = 0; mig < 8; mig++) {
            const int s = m0 + wr * 128 + mig * 16 + l15;
            float4 v;
            v.x = acc[mig][nj][0] + bv4.x;
            v.y = acc[mig][nj][1] + bv4.y;
            v.z = acc[mig][nj][2] + bv4.z;
            v.w = acc[mig][nj][3] + bv4.w;
            *(float4*)(out + (size_t)s * 1024 + nbase) = v;
        }
    }
}

// ---------------- attention v5 (unchanged, r1-validated) ----------------

__global__ __launch_bounds__(256) void attn3(
    const unsigned short* __restrict__ qws,
    const unsigned short* __restrict__ kws,
    const unsigned short* __restrict__ vtw,   // [bh][64][2048]
    unsigned short* __restrict__ zb)          // [8192][1024], col = h*64+d
{
    __shared__ __align__(16) unsigned short Ks[64 * 64];
    __shared__ __align__(16) unsigned short Vs[64 * 64];    // [d][key]
    __shared__ __align__(16) unsigned short Ps[4 * 16 * 64];

    const int t = threadIdx.x;
    const int lane = t & 63;
    const int w = t >> 6;
    const int quad = lane >> 4;
    const int l15 = lane & 15;
    const int hi = l15 >> 3;
    const int lo = l15 & 7;

    const int qt = 31 - (blockIdx.x >> 6);   // longest blocks dispatched first
    const int bh = blockIdx.x & 63;
    const int q0 = qt * 64;
    const int qbase = q0 + w * 16;
    const size_t base = (size_t)bh * SS * DHEAD;
    const unsigned short* Q = qws + base;
    const unsigned short* K = kws + base;
    const unsigned short* Vt = vtw + base;   // [64][2048]

    bf16x8 qf0 = *(const bf16x8*)(Q + (size_t)(qbase + l15) * 64 + quad * 8);
    bf16x8 qf1 = *(const bf16x8*)(Q + (size_t)(qbase + l15) * 64 + 32 + quad * 8);

    f32x4 o[4] = {};          // swapped PV: o[dt] rows = d (dt*16+quad*4+r), col = q (l15)
    float lsum[4] = {0.f, 0.f, 0.f, 0.f};
    unsigned short* Pw = Ps + w * 16 * 64;

    // staging: thread t covers row sr, original col-granules (t&3) and (t&3)+4
    const int sr = t >> 2;
    const int g0 = t & 3;
    const int sw0 = ((g0 ^ (sr & 7)) << 3);
    const int sw1 = (((g0 + 4) ^ (sr & 7)) << 3);
    unsigned short* ksw = Ks + sr * 64;
    unsigned short* vsw = Vs + sr * 64;
    const unsigned short* Kg = K + (size_t)sr * 64 + g0 * 8;
    const unsigned short* Vg = Vt + (size_t)sr * 2048 + g0 * 8;

    // fragment reads: want original granules quad / quad+4 of row with row&7==l15&7
    const int gq0 = ((quad ^ lo) << 3);
    const int gq1 = (((quad + 4) ^ lo) << 3);

    const int nch = qt + 1;

    // prologue: prefetch chunk 0 into registers
    uint4 kr0 = *(const uint4*)(Kg);
    uint4 kr1 = *(const uint4*)(Kg + 32);
    uint4 vr0 = *(const uint4*)(Vg);
    uint4 vr1 = *(const uint4*)(Vg + 32);

    for (int c = 0; c < nch; c++) {
        __builtin_amdgcn_sched_barrier(0);
        __builtin_amdgcn_s_barrier();          // LDS free: all waves consumed chunk c-1
        *(uint4*)(ksw + sw0) = kr0;
        *(uint4*)(ksw + sw1) = kr1;
        *(uint4*)(vsw + sw0) = vr0;
        *(uint4*)(vsw + sw1) = vr1;
        if (c + 1 < nch) {                     // issue next chunk's loads; NOT waited here
            const unsigned short* kp = Kg + (size_t)(c + 1) * 64 * 64;
            const unsigned short* vp = Vg + (size_t)(c + 1) * 64;
            kr0 = *(const uint4*)(kp);
            kr1 = *(const uint4*)(kp + 32);
            vr0 = *(const uint4*)(vp);
            vr1 = *(const uint4*)(vp + 32);
        }
        asm volatile("s_waitcnt lgkmcnt(0)" ::: "memory");   // my ds_writes done (vmcnt stays)
        __builtin_amdgcn_s_barrier();          // LDS ready
        __builtin_amdgcn_sched_barrier(0);

        // scores for 16 q-rows x 64 keys: 8 MFMA (D: row=q quad*4+r, col=key l15)
        f32x4 s[4];
        __builtin_amdgcn_s_setprio(1);
#pragma unroll
        for (int sub = 0; sub < 4; sub++) {
            const unsigned short* kr = Ks + (sub * 16 + l15) * 64;
            bf16x8 kf0 = *(const bf16x8*)(kr + gq0);
            bf16x8 kf1 = *(const bf16x8*)(kr + gq1);
            f32x4 sv = {};
            sv = __builtin_amdgcn_mfma_f32_16x16x32_bf16(qf0, kf0, sv, 0, 0, 0);
            sv = __builtin_amdgcn_mfma_f32_16x16x32_bf16(qf1, kf1, sv, 0, 0, 0);
            s[sub] = sv;
        }
        __builtin_amdgcn_s_setprio(0);

        // fixed-max softmax: p = exp2(s) since Q carries 0.125*log2e
        const int kb = c * 64;
        if (c == nch - 1) {
            const int qg = qbase + quad * 4;
#pragma unroll
            for (int sub = 0; sub < 4; sub++) {
                const int key = kb + sub * 16 + l15;
#pragma unroll
                for (int r = 0; r < 4; r++) {
                    float p = (key > qg + r) ? 0.f : exp2f(s[sub][r]);
                    lsum[r] += p;
                    const int q = quad * 4 + r;
                    Pw[q * 64 + (((sub * 2 + hi) ^ (q & 7)) << 3) + lo] = f2bf(p);
                }
            }
        } else {
#pragma unroll
            for (int sub = 0; sub < 4; sub++)
#pragma unroll
                for (int r = 0; r < 4; r++) {
                    float p = exp2f(s[sub][r]);
                    lsum[r] += p;
                    const int q = quad * 4 + r;
                    Pw[q * 64 + (((sub * 2 + hi) ^ (q & 7)) << 3) + lo] = f2bf(p);
                }
        }
        // wave-private D-layout -> fragment-layout round trip
        asm volatile("s_waitcnt lgkmcnt(0)" ::: "memory");
        bf16x8 pf0 = *(const bf16x8*)(Pw + l15 * 64 + gq0);
        bf16x8 pf1 = *(const bf16x8*)(Pw + l15 * 64 + gq1);
        __builtin_amdgcn_s_setprio(1);
#pragma unroll
        for (int dt = 0; dt < 4; dt++) {
            const unsigned short* vrp = Vs + (dt * 16 + l15) * 64;
            bf16x8 vf0 = *(const bf16x8*)(vrp + gq0);
            bf16x8 vf1 = *(const bf16x8*)(vrp + gq1);
            // swapped: A=V (m=d), B=P (n=q)
            o[dt] = __builtin_amdgcn_mfma_f32_16x16x32_bf16(vf0, pf0, o[dt], 0, 0, 0);
            o[dt] = __builtin_amdgcn_mfma_f32_16x16x32_bf16(vf1, pf1, o[dt], 0, 0, 0);
        }
        __builtin_amdgcn_s_setprio(0);
    }

    // full row sums (valid per lane for q = quad*4+r after 16-lane reduce)
#pragma unroll
    for (int r = 0; r < 4; r++) {
        float v = lsum[r];
        v += __shfl_xor(v, 1);
        v += __shfl_xor(v, 2);
        v += __shfl_xor(v, 4);
        v += __shfl_xor(v, 8);
        lsum[r] = v;
    }
    // redistribute: this lane needs 1/sum for q = l15
    const int srcl = (l15 >> 2) << 4;
    float t0 = __shfl(lsum[0], srcl);
    float t1 = __shfl(lsum[1], srcl);
    float t2 = __shfl(lsum[2], srcl);
    float t3 = __shfl(lsum[3], srcl);
    const int rr = l15 & 3;
    float den = (rr == 0) ? t0 : (rr == 1) ? t1 : (rr == 2) ? t2 : t3;
    const float inv = 1.0f / den;

    const int b = bh >> 4, h = bh & 15;
    const int q = qbase + l15;
    unsigned short* zrow = zb + (size_t)(b * 2048 + q) * 1024 + h * 64 + quad * 4;
#pragma unroll
    for (int dt = 0; dt < 4; dt++) {
        unsigned short pk[4];
#pragma unroll
        for (int r = 0; r < 4; r++) pk[r] = f2bf(o[dt][r] * inv);
        *(uint2*)(zrow + dt * 16) = *(uint2*)pk;
    }
}

// ---------------- launch ----------------

extern "C" void kernel_launch(void* const* d_in, const int* in_sizes, int n_in,
                              void* d_out, int out_size, void* d_ws, size_t ws_size,
                              hipStream_t stream) {
    const float* x  = (const float*)d_in[0];
    const float* WQ = (const float*)d_in[1];
    const float* WK = (const float*)d_in[2];
    const float* WV = (const float*)d_in[3];
    const float* WO = (const float*)d_in[4];
    const float* bQ = (const float*)d_in[5];
    const float* bK = (const float*)d_in[6];
    const float* bV = (const float*)d_in[7];
    const float* bO = (const float*)d_in[8];
    float* out = (float*)d_out;

    char* ws = (char*)d_ws;
    unsigned short* xb   = (unsigned short*)ws;                   // 16 MB (reused as zbuf)
    unsigned short* wqkv = (unsigned short*)(ws + (16u << 20));   // 6 MB
    unsigned short* woT  = (unsigned short*)(ws + (22u << 20));   // 2 MB
    unsigned short* qws  = (unsigned short*)(ws + (24u << 20));   // 16 MB
    unsigned short* kws  = (unsigned short*)(ws + (40u << 20));   // 16 MB
    unsigned short* vtw  = (unsigned short*)(ws + (56u << 20));   // 16 MB, [bh][64][2048]
    unsigned short* zbuf = xb;                                    // x dead after gemm_qkv

    pack_x<<<8192, 256, 0, stream>>>(x, xb);
    pack_wqkv<<<(3072 * 1024) / 256, 256, 0, stream>>>(WQ, WK, WV, wqkv);
    pack_wo<<<(1024 * 1024) / 256, 256, 0, stream>>>(WO, woT);
    gemm_qkv8<<<dim3(12, 32), 512, 0, stream>>>(xb, wqkv, bQ, bK, bV, qws, kws, vtw);
    attn3<<<2048, 256, 0, stream>>>(qws, kws, vtw, zbuf);
    gemm_out8<<<dim3(4, 32), 512, 0, stream>>>(zbuf, woT, bO, out);
}

// Round 6
// 289.438 us; speedup vs baseline: 1.0580x; 1.0564x over previous
//
#include <hip/hip_runtime.h>
#include <hip/hip_bf16.h>
#include <math.h>

typedef __bf16 bf16_t;
typedef bf16_t bf16x8 __attribute__((ext_vector_type(8)));
typedef float f32x4 __attribute__((ext_vector_type(4)));

#define BB 4
#define SS 2048
#define HH 16
#define DMODEL 1024
#define DHEAD 64

// Q is pre-scaled by 1/sqrt(64) * log2(e) so attention probs are exp2(q.k)
#define QSCALE 0.18033688011112042f

__device__ inline unsigned short f2bf(float f) {
    union { __hip_bfloat16 h; unsigned short u; } cvt;
    cvt.h = __float2bfloat16(f);
    return cvt.u;
}

// async global->LDS, 16B per lane. LDS dest = wave-uniform base + lane*16.
__device__ __forceinline__ void gll16(const unsigned short* g, unsigned short* l) {
    __builtin_amdgcn_global_load_lds(
        (const __attribute__((address_space(1))) unsigned int*)(g),
        (__attribute__((address_space(3))) unsigned int*)(l), 16, 0, 0);
}

// ---------------- fused pack kernel (one dispatch instead of three) ----------------

__global__ void pack_all(const float* __restrict__ x,
                         const float* __restrict__ wq, const float* __restrict__ wk,
                         const float* __restrict__ wv, const float* __restrict__ wo,
                         unsigned short* __restrict__ xb, unsigned short* __restrict__ wqkv,
                         unsigned short* __restrict__ woT) {
    const int bid = blockIdx.x;
    if (bid < 8192) {
        // x [4,2048,1024] f32 -> bf16
        int i = bid * 256 + threadIdx.x;
        const float4 v = ((const float4*)x)[i];
        unsigned short o[4] = { f2bf(v.x), f2bf(v.y), f2bf(v.z), f2bf(v.w) };
        *(uint2*)(xb + 4 * (size_t)i) = *(uint2*)o;
    } else if (bid < 8192 + 12288) {
        // WqkvT[n][k], n = mat*1024 + h*64 + d, k = m.  W_* is [H][DM][DH].
        int idx = (bid - 8192) * 256 + threadIdx.x;
        int k  = idx & 1023;
        int n  = idx >> 10;
        int mat = n >> 10;
        int n1 = n & 1023;
        int h = n1 >> 6, d = n1 & 63;
        const float* wsrc = (mat == 0) ? wq : (mat == 1) ? wk : wv;
        wqkv[idx] = f2bf(wsrc[(h << 16) + (k << 6) + d]);
    } else {
        // WoT[n][k], n = m_model, k = h*64+dh.  W_O is [H][DH][DM] = row-major [k][n].
        int idx = (bid - 20480) * 256 + threadIdx.x;
        int k = idx & 1023, n = idx >> 10;
        woT[idx] = f2bf(wo[(k << 10) + n]);
    }
}

// ---------------- 256x256 8-phase K-loop (frozen from round 5) ----------------

template <bool SWAP>
__device__ __forceinline__ void mf16(f32x4& d, bf16x8 a, bf16x8 b) {
    if constexpr (SWAP)
        d = __builtin_amdgcn_mfma_f32_16x16x32_bf16(b, a, d, 0, 0, 0);  // D rows = n
    else
        d = __builtin_amdgcn_mfma_f32_16x16x32_bf16(a, b, d, 0, 0, 0);  // D rows = m
}

#define GBAR()   __builtin_amdgcn_s_barrier()
#define SCHEDB() __builtin_amdgcn_sched_barrier(0)
#define WLGKM0() asm volatile("s_waitcnt lgkmcnt(0)" ::: "memory")

__device__ __forceinline__ void stage2(const unsigned short* g, unsigned short* lb,
                                       int T, int w) {
    const unsigned short* s = g + T * 64;
    gll16(s, lb + w * 8 * 64);
    gll16(s + 64 * 1024, lb + (64 + w * 8) * 64);
}

template <bool SWAP>
__device__ __forceinline__ void ktstep(
    unsigned short (*Ac)[64], unsigned short (*Bc)[64],   // current tile buffers
    unsigned short (*An)[64], unsigned short (*Bn)[64],   // next tile buffers
    const unsigned short* gA0, const unsigned short* gA1,
    const unsigned short* gB0, const unsigned short* gB1,
    int kt, int w, int wr, int wc, int l15, int quad, int lo,
    f32x4 (&acc)[8][4])
{
    bf16x8 a0f[4][2], a1f[4][2], bAf[2][2], bBf[2][2];
    const int c0 = (quad ^ lo) * 8;
    const int c1 = ((4 | quad) ^ lo) * 8;

    // ---- p0: reads a0 (8) + bA (4); stage (t+1).B1hi
#pragma unroll
    for (int mi = 0; mi < 4; mi++) {
        a0f[mi][0] = *(const bf16x8*)&Ac[wr * 128 + mi * 16 + l15][c0];
        a0f[mi][1] = *(const bf16x8*)&Ac[wr * 128 + mi * 16 + l15][c1];
    }
#pragma unroll
    for (int nj = 0; nj < 2; nj++) {
        bAf[nj][0] = *(const bf16x8*)&Bc[wc * 64 + nj * 16 + l15][c0];
        bAf[nj][1] = *(const bf16x8*)&Bc[wc * 64 + nj * 16 + l15][c1];
    }
    if (kt + 1 < 16) stage2(gB1, &Bn[128][0], kt + 1, w);
    GBAR();
    WLGKM0();
    SCHEDB();
    __builtin_amdgcn_s_setprio(1);
#pragma unroll
    for (int mi = 0; mi < 4; mi++)
#pragma unroll
        for (int nj = 0; nj < 2; nj++) {
            mf16<SWAP>(acc[mi][nj], a0f[mi][0], bAf[nj][0]);
            mf16<SWAP>(acc[mi][nj], a0f[mi][1], bAf[nj][1]);
        }
    __builtin_amdgcn_s_setprio(0);
    SCHEDB();
    GBAR();

    // ---- p1: reads bB (4); stage (t+1).A1hi
#pragma unroll
    for (int nj = 0; nj < 2; nj++) {
        bBf[nj][0] = *(const bf16x8*)&Bc[wc * 64 + (nj + 2) * 16 + l15][c0];
        bBf[nj][1] = *(const bf16x8*)&Bc[wc * 64 + (nj + 2) * 16 + l15][c1];
    }
    if (kt + 1 < 16) stage2(gA1, &An[128][0], kt + 1, w);
    GBAR();
    WLGKM0();
    SCHEDB();
    __builtin_amdgcn_s_setprio(1);
#pragma unroll
    for (int mi = 0; mi < 4; mi++)
#pragma unroll
        for (int nj = 0; nj < 2; nj++) {
            mf16<SWAP>(acc[mi][nj + 2], a0f[mi][0], bBf[nj][0]);
            mf16<SWAP>(acc[mi][nj + 2], a0f[mi][1], bBf[nj][1]);
        }
    __builtin_amdgcn_s_setprio(0);
    SCHEDB();
    GBAR();

    // ---- p2: reads a1 (8); stage (t+2).B0lo (into Bc: its lower half is dead)
#pragma unroll
    for (int mi = 0; mi < 4; mi++) {
        a1f[mi][0] = *(const bf16x8*)&Ac[wr * 128 + 64 + mi * 16 + l15][c0];
        a1f[mi][1] = *(const bf16x8*)&Ac[wr * 128 + 64 + mi * 16 + l15][c1];
    }
    if (kt + 2 < 16) stage2(gB0, &Bc[0][0], kt + 2, w);
    GBAR();
    WLGKM0();
    SCHEDB();
    __builtin_amdgcn_s_setprio(1);
#pragma unroll
    for (int mi = 0; mi < 4; mi++)
#pragma unroll
        for (int nj = 0; nj < 2; nj++) {
            mf16<SWAP>(acc[4 + mi][nj + 2], a1f[mi][0], bBf[nj][0]);
            mf16<SWAP>(acc[4 + mi][nj + 2], a1f[mi][1], bBf[nj][1]);
        }
    __builtin_amdgcn_s_setprio(0);
    SCHEDB();
    GBAR();

    // ---- p3: no reads; stage (t+2).A0lo; boundary wait
    if (kt + 2 < 16) stage2(gA0, &Ac[0][0], kt + 2, w);
    GBAR();
    WLGKM0();
    SCHEDB();
    __builtin_amdgcn_s_setprio(1);
#pragma unroll
    for (int mi = 0; mi < 4; mi++)
#pragma unroll
        for (int nj = 0; nj < 2; nj++) {
            mf16<SWAP>(acc[4 + mi][nj], a1f[mi][0], bAf[nj][0]);
            mf16<SWAP>(acc[4 + mi][nj], a1f[mi][1], bAf[nj][1]);
        }
    __builtin_amdgcn_s_setprio(0);
    SCHEDB();
    if (kt == 14) {
        asm volatile("s_waitcnt vmcnt(0)" ::: "memory");   // last staged tile: drain all
    } else if (kt < 14) {
        asm volatile("s_waitcnt vmcnt(4)" ::: "memory");   // keep 2 half-tiles in flight
    }
    GBAR();
}

template <bool SWAP>
__device__ __forceinline__ void kloop256(
    unsigned short (*A0)[64], unsigned short (*A1)[64],
    unsigned short (*B0)[64], unsigned short (*B1)[64],
    const unsigned short* gA0, const unsigned short* gA1,
    const unsigned short* gB0, const unsigned short* gB1,
    int w, int wr, int wc, int l15, int quad, int lo,
    f32x4 (&acc)[8][4])
{
    // prologue: stream order (0).B0,(0).A0,(0).B1,(0).A1,(1).B0,(1).A0
    stage2(gB0, &B0[0][0],   0, w);
    stage2(gA0, &A0[0][0],   0, w);
    stage2(gB1, &B0[128][0], 0, w);
    stage2(gA1, &A0[128][0], 0, w);
    stage2(gB0, &B1[0][0],   1, w);
    stage2(gA0, &A1[0][0],   1, w);
    asm volatile("s_waitcnt vmcnt(4)" ::: "memory");   // tile0 fully landed
    GBAR();

    for (int i = 0; i < 8; ++i) {
        ktstep<SWAP>(A0, B0, A1, B1, gA0, gA1, gB0, gB1, 2 * i,     w, wr, wc, l15, quad, lo, acc);
        ktstep<SWAP>(A1, B1, A0, B0, gA0, gA1, gB0, gB1, 2 * i + 1, w, wr, wc, l15, quad, lo, acc);
    }
}

// ---------------- GEMM 1: qkv = x @ WqkvT^T + bias ----------------

__global__ __launch_bounds__(512, 2) void gemm_qkv8(
    const unsigned short* __restrict__ xb,    // [8192][1024]
    const unsigned short* __restrict__ wT,    // [3072][1024]
    const float* __restrict__ bq, const float* __restrict__ bk, const float* __restrict__ bv,
    unsigned short* __restrict__ qws, unsigned short* __restrict__ kws,
    unsigned short* __restrict__ vtw)         // [64][64][2048]
{
    __shared__ __align__(16) unsigned short A0s[256][64];   // 4 x 32 KiB, distinct objects
    __shared__ __align__(16) unsigned short A1s[256][64];
    __shared__ __align__(16) unsigned short B0s[256][64];
    __shared__ __align__(16) unsigned short B1s[256][64];

    const int t = threadIdx.x;
    const int lane = t & 63;
    const int w = t >> 6;            // 0..7
    const int quad = lane >> 4;
    const int l15 = lane & 15;
    const int lo = l15 & 7;
    const int wr = w >> 2;           // 0..1
    const int wc = w & 3;            // 0..3
    const int n0 = blockIdx.x * 256;
    const int m0 = blockIdx.y * 256;
    const int mat = n0 >> 10;        // uniform per block (256 | 1024)

    // staging source: lane covers row w*8+(lane>>3), source granule (lane&7)^(lane>>3)
    const int sr8 = lane >> 3;
    const size_t soff = (size_t)(w * 8 + sr8) * 1024 + (size_t)(((lane & 7) ^ sr8) * 8);
    const unsigned short* gA0 = xb + (size_t)m0 * 1024 + soff;
    const unsigned short* gA1 = xb + (size_t)(m0 + 128) * 1024 + soff;
    const unsigned short* gB0 = wT + (size_t)n0 * 1024 + soff;
    const unsigned short* gB1 = wT + (size_t)(n0 + 128) * 1024 + soff;

    f32x4 acc[8][4] = {};

    const int b = m0 >> 11;
    const int m0r = m0 & 2047;

    if (mat != 2) {
        kloop256<true>(A0s, A1s, B0s, B1s, gA0, gA1, gB0, gB1, w, wr, wc, l15, quad, lo, acc);
        // swapped D: lane holds 4 consecutive n (=d) at fixed s -> uint2 stores
        const float* bias_p = (mat == 0) ? bq : bk;
        const float scale = (mat == 0) ? QSCALE : 1.0f;
        unsigned short* dst = (mat == 0) ? qws : kws;
#pragma unroll
        for (int nj = 0; nj < 4; nj++) {
            const int noff = wc * 64 + nj * 16 + quad * 4;     // 0..255
            const int nmat = (n0 & 1023) + noff;
            const int h = nmat >> 6;
            const int dbase = nmat & 63;
            const float4 bv4 = *(const float4*)(bias_p + h * 64 + dbase);
            const float bias_r[4] = { bv4.x, bv4.y, bv4.z, bv4.w };
#pragma unroll
            for (int mig = 0; mig < 8; mig++) {
                const int s = m0r + wr * 128 + mig * 16 + l15;
                unsigned short pk[4];
#pragma unroll
                for (int r = 0; r < 4; r++) pk[r] = f2bf((acc[mig][nj][r] + bias_r[r]) * scale);
                *(uint2*)(dst + (size_t)((b * 16 + h) * 2048 + s) * 64 + dbase) = *(uint2*)pk;
            }
        }
    } else {
        kloop256<false>(A0s, A1s, B0s, B1s, gA0, gA1, gB0, gB1, w, wr, wc, l15, quad, lo, acc);
        // normal D: lane holds 4 consecutive s at fixed n -> uint2 into V^T
#pragma unroll
        for (int nj = 0; nj < 4; nj++) {
            const int n1 = (n0 & 1023) + wc * 64 + nj * 16 + l15;
            const int h = n1 >> 6, d = n1 & 63;
            const float bias = bv[h * 64 + d];
#pragma unroll
            for (int mig = 0; mig < 8; mig++) {
                const int s0 = m0r + wr * 128 + mig * 16 + quad * 4;
                unsigned short pk[4];
#pragma unroll
                for (int r = 0; r < 4; r++) pk[r] = f2bf(acc[mig][nj][r] + bias);
                *(uint2*)(vtw + ((size_t)(b * 16 + h) * 64 + d) * 2048 + s0) = *(uint2*)pk;
            }
        }
    }
}

// ---------------- GEMM 2: out = z @ WoT^T + bO (same template) ----------------

__global__ __launch_bounds__(512, 2) void gemm_out8(
    const unsigned short* __restrict__ zb,    // [8192][1024]
    const unsigned short* __restrict__ wT,    // [1024][1024]
    const float* __restrict__ bo,
    float* __restrict__ out)
{
    __shared__ __align__(16) unsigned short A0s[256][64];
    __shared__ __align__(16) unsigned short A1s[256][64];
    __shared__ __align__(16) unsigned short B0s[256][64];
    __shared__ __align__(16) unsigned short B1s[256][64];

    const int t = threadIdx.x;
    const int lane = t & 63;
    const int w = t >> 6;
    const int quad = lane >> 4;
    const int l15 = lane & 15;
    const int lo = l15 & 7;
    const int wr = w >> 2;
    const int wc = w & 3;
    const int n0 = blockIdx.x * 256;
    const int m0 = blockIdx.y * 256;

    const int sr8 = lane >> 3;
    const size_t soff = (size_t)(w * 8 + sr8) * 1024 + (size_t)(((lane & 7) ^ sr8) * 8);
    const unsigned short* gA0 = zb + (size_t)m0 * 1024 + soff;
    const unsigned short* gA1 = zb + (size_t)(m0 + 128) * 1024 + soff;
    const unsigned short* gB0 = wT + (size_t)n0 * 1024 + soff;
    const unsigned short* gB1 = wT + (size_t)(n0 + 128) * 1024 + soff;

    f32x4 acc[8][4] = {};

    kloop256<true>(A0s, A1s, B0s, B1s, gA0, gA1, gB0, gB1, w, wr, wc, l15, quad, lo, acc);

    // swapped D: lane holds 4 consecutive n at fixed s -> float4 stores
#pragma unroll
    for (int nj = 0; nj < 4; nj++) {
        const int nbase = n0 + wc * 64 + nj * 16 + quad * 4;
        const float4 bv4 = *(const float4*)(bo + nbase);
#pragma unroll
        for (int mig = 0; mig < 8; mig++) {
            const int s = m0 + wr * 128 + mig * 16 + l15;
            float4 v;
            v.x = acc[mig][nj][0] + bv4.x;
            v.y = acc[mig][nj][1] + bv4.y;
            v.z = acc[mig][nj][2] + bv4.z;
            v.w = acc[mig][nj][3] + bv4.w;
            *(float4*)(out + (size_t)s * 1024 + nbase) = v;
        }
    }
}

// ---------------- attention v6: swapped QK^T -> packed b64 P-writes ----------------
// mfma(K,Q) gives S[key][q=l15]: lane holds 4 CONSECUTIVE keys (quad*4+r) at fixed
// q, so the P store is 4x ds_write_b64 to loop-invariant addresses (was 16 scattered
// ds_write_b16 + ~48 addr-VALU). 8B-slot swizzle slot^=(lo<<1) keeps the existing
// b128 read addresses (granule^lo) valid: even XOR mask preserves slot-pair
// adjacency, so granule g lands at granule g^lo with byte order intact. Row-sum
// is now a single scalar per lane + shfl_xor(16/32); no redistribution.

__global__ __launch_bounds__(256) void attn3(
    const unsigned short* __restrict__ qws,
    const unsigned short* __restrict__ kws,
    const unsigned short* __restrict__ vtw,   // [bh][64][2048]
    unsigned short* __restrict__ zb)          // [8192][1024], col = h*64+d
{
    __shared__ __align__(16) unsigned short Ks[64 * 64];
    __shared__ __align__(16) unsigned short Vs[64 * 64];    // [d][key]
    __shared__ __align__(16) unsigned short Ps[4 * 16 * 64]; // per-wave [q=16][key=64]

    const int t = threadIdx.x;
    const int lane = t & 63;
    const int w = t >> 6;
    const int quad = lane >> 4;
    const int l15 = lane & 15;
    const int lo = l15 & 7;

    const int qt = 31 - (blockIdx.x >> 6);   // longest blocks dispatched first
    const int bh = blockIdx.x & 63;
    const int q0 = qt * 64;
    const int qbase = q0 + w * 16;
    const size_t base = (size_t)bh * SS * DHEAD;
    const unsigned short* Q = qws + base;
    const unsigned short* K = kws + base;
    const unsigned short* Vt = vtw + base;   // [64][2048]

    bf16x8 qf0 = *(const bf16x8*)(Q + (size_t)(qbase + l15) * 64 + quad * 8);
    bf16x8 qf1 = *(const bf16x8*)(Q + (size_t)(qbase + l15) * 64 + 32 + quad * 8);

    f32x4 o[4] = {};          // swapped PV: o[dt] rows = d (dt*16+quad*4+r), col = q (l15)
    float lsum = 0.f;         // row-sum for q = qbase + l15
    unsigned short* Pw = Ps + w * 16 * 64;

    // staging: thread t covers row sr, original col-granules (t&3) and (t&3)+4
    const int sr = t >> 2;
    const int g0 = t & 3;
    const int sw0 = ((g0 ^ (sr & 7)) << 3);
    const int sw1 = (((g0 + 4) ^ (sr & 7)) << 3);
    unsigned short* ksw = Ks + sr * 64;
    unsigned short* vsw = Vs + sr * 64;
    const unsigned short* Kg = K + (size_t)sr * 64 + g0 * 8;
    const unsigned short* Vg = Vt + (size_t)sr * 2048 + g0 * 8;

    // fragment reads: want original granules quad / quad+4 of row with row&7==l15&7
    const int gq0 = ((quad ^ lo) << 3);
    const int gq1 = (((quad + 4) ^ lo) << 3);

    // P write pointers (loop-invariant): row q=l15, 8B slot (sub*4+quad)^(lo<<1)
    unsigned short* pwr = Pw + l15 * 64;
    unsigned short* pws0 = pwr + (((0 + quad) ^ (lo << 1)) << 2);
    unsigned short* pws1 = pwr + (((4 + quad) ^ (lo << 1)) << 2);
    unsigned short* pws2 = pwr + (((8 + quad) ^ (lo << 1)) << 2);
    unsigned short* pws3 = pwr + (((12 + quad) ^ (lo << 1)) << 2);

    const int nch = qt + 1;

    // prologue: prefetch chunk 0 into registers
    uint4 kr0 = *(const uint4*)(Kg);
    uint4 kr1 = *(const uint4*)(Kg + 32);
    uint4 vr0 = *(const uint4*)(Vg);
    uint4 vr1 = *(const uint4*)(Vg + 32);

    for (int c = 0; c < nch; c++) {
        __builtin_amdgcn_sched_barrier(0);
        __builtin_amdgcn_s_barrier();          // LDS free: all waves consumed chunk c-1
        *(uint4*)(ksw + sw0) = kr0;
        *(uint4*)(ksw + sw1) = kr1;
        *(uint4*)(vsw + sw0) = vr0;
        *(uint4*)(vsw + sw1) = vr1;
        if (c + 1 < nch) {                     // issue next chunk's loads; NOT waited here
            const unsigned short* kp = Kg + (size_t)(c + 1) * 64 * 64;
            const unsigned short* vp = Vg + (size_t)(c + 1) * 64;
            kr0 = *(const uint4*)(kp);
            kr1 = *(const uint4*)(kp + 32);
            vr0 = *(const uint4*)(vp);
            vr1 = *(const uint4*)(vp + 32);
        }
        asm volatile("s_waitcnt lgkmcnt(0)" ::: "memory");   // my ds_writes done (vmcnt stays)
        __builtin_amdgcn_s_barrier();          // LDS ready
        __builtin_amdgcn_sched_barrier(0);

        // scores, SWAPPED: A=K, B=Q -> D[row=key quad*4+r][col=q l15]
        f32x4 s[4];
        __builtin_amdgcn_s_setprio(1);
#pragma unroll
        for (int sub = 0; sub < 4; sub++) {
            const unsigned short* kr = Ks + (sub * 16 + l15) * 64;
            bf16x8 kf0 = *(const bf16x8*)(kr + gq0);
            bf16x8 kf1 = *(const bf16x8*)(kr + gq1);
            f32x4 sv = {};
            sv = __builtin_amdgcn_mfma_f32_16x16x32_bf16(kf0, qf0, sv, 0, 0, 0);
            sv = __builtin_amdgcn_mfma_f32_16x16x32_bf16(kf1, qf1, sv, 0, 0, 0);
            s[sub] = sv;
        }
        __builtin_amdgcn_s_setprio(0);

        // fixed-max softmax: p = exp2(s); lane covers keys k0..k0+3 at q=qbase+l15
        const int kb = c * 64;
        if (c == nch - 1) {
            const int qg = qbase + l15;
#pragma unroll
            for (int sub = 0; sub < 4; sub++) {
                const int k0 = kb + sub * 16 + quad * 4;
                unsigned short pk[4];
#pragma unroll
                for (int r = 0; r < 4; r++) {
                    float p = (k0 + r > qg) ? 0.f : exp2f(s[sub][r]);
                    lsum += p;
                    pk[r] = f2bf(p);
                }
                unsigned short* wp = (sub == 0) ? pws0 : (sub == 1) ? pws1 : (sub == 2) ? pws2 : pws3;
                *(uint2*)wp = *(uint2*)pk;
            }
        } else {
#pragma unroll
            for (int sub = 0; sub < 4; sub++) {
                unsigned short pk[4];
#pragma unroll
                for (int r = 0; r < 4; r++) {
                    float p = exp2f(s[sub][r]);
                    lsum += p;
                    pk[r] = f2bf(p);
                }
                unsigned short* wp = (sub == 0) ? pws0 : (sub == 1) ? pws1 : (sub == 2) ? pws2 : pws3;
                *(uint2*)wp = *(uint2*)pk;
            }
        }
        // wave-private write -> fragment read (same wave, cross-lane): drain DS
        asm volatile("s_waitcnt lgkmcnt(0)" ::: "memory");
        bf16x8 pf0 = *(const bf16x8*)(Pw + l15 * 64 + gq0);
        bf16x8 pf1 = *(const bf16x8*)(Pw + l15 * 64 + gq1);
        __builtin_amdgcn_s_setprio(1);
#pragma unroll
        for (int dt = 0; dt < 4; dt++) {
            const unsigned short* vrp = Vs + (dt * 16 + l15) * 64;
            bf16x8 vf0 = *(const bf16x8*)(vrp + gq0);
            bf16x8 vf1 = *(const bf16x8*)(vrp + gq1);
            // swapped: A=V (m=d), B=P (n=q)
            o[dt] = __builtin_amdgcn_mfma_f32_16x16x32_bf16(vf0, pf0, o[dt], 0, 0, 0);
            o[dt] = __builtin_amdgcn_mfma_f32_16x16x32_bf16(vf1, pf1, o[dt], 0, 0, 0);
        }
        __builtin_amdgcn_s_setprio(0);
    }

    // row sum for q = l15: reduce across the 4 quad-groups (lanes l15+16k)
    float v = lsum;
    v += __shfl_xor(v, 16);
    v += __shfl_xor(v, 32);
    const float inv = 1.0f / v;

    const int b = bh >> 4, h = bh & 15;
    const int q = qbase + l15;
    unsigned short* zrow = zb + (size_t)(b * 2048 + q) * 1024 + h * 64 + quad * 4;
#pragma unroll
    for (int dt = 0; dt < 4; dt++) {
        unsigned short pk[4];
#pragma unroll
        for (int r = 0; r < 4; r++) pk[r] = f2bf(o[dt][r] * inv);
        *(uint2*)(zrow + dt * 16) = *(uint2*)pk;
    }
}

// ---------------- launch ----------------

extern "C" void kernel_launch(void* const* d_in, const int* in_sizes, int n_in,
                              void* d_out, int out_size, void* d_ws, size_t ws_size,
                              hipStream_t stream) {
    const float* x  = (const float*)d_in[0];
    const float* WQ = (const float*)d_in[1];
    const float* WK = (const float*)d_in[2];
    const float* WV = (const float*)d_in[3];
    const float* WO = (const float*)d_in[4];
    const float* bQ = (const float*)d_in[5];
    const float* bK = (const float*)d_in[6];
    const float* bV = (const float*)d_in[7];
    const float* bO = (const float*)d_in[8];
    float* out = (float*)d_out;

    char* ws = (char*)d_ws;
    unsigned short* xb   = (unsigned short*)ws;                   // 16 MB (reused as zbuf)
    unsigned short* wqkv = (unsigned short*)(ws + (16u << 20));   // 6 MB
    unsigned short* woT  = (unsigned short*)(ws + (22u << 20));   // 2 MB
    unsigned short* qws  = (unsigned short*)(ws + (24u << 20));   // 16 MB
    unsigned short* kws  = (unsigned short*)(ws + (40u << 20));   // 16 MB
    unsigned short* vtw  = (unsigned short*)(ws + (56u << 20));   // 16 MB, [bh][64][2048]
    unsigned short* zbuf = xb;                                    // x dead after gemm_qkv

    pack_all<<<24576, 256, 0, stream>>>(x, WQ, WK, WV, WO, xb, wqkv, woT);
    gemm_qkv8<<<dim3(12, 32), 512, 0, stream>>>(xb, wqkv, bQ, bK, bV, qws, kws, vtw);
    attn3<<<2048, 256, 0, stream>>>(qws, kws, vtw, zbuf);
    gemm_out8<<<dim3(4, 32), 512, 0, stream>>>(zbuf, woT, bO, out);
}